// Round 1
// baseline (936.606 us; speedup 1.0000x reference)
//
#include <hip/hip_runtime.h>
#include <hip/hip_bf16.h>
#include <cstdint>
#include <cstddef>

typedef __hip_bfloat16 BF16;
typedef __bf16 bf16x8 __attribute__((ext_vector_type(8)));
typedef float floatx4 __attribute__((ext_vector_type(4)));

// ---------------- workspace layout (bytes) ----------------
static constexpr size_t OFF_WQKV  = 0;
static constexpr size_t OFF_WPROJ = OFF_WQKV  + (size_t)1536 * 512 * 2;   // qkv_w^T bf16
static constexpr size_t OFF_W1    = OFF_WPROJ + (size_t)512 * 512 * 2;    // proj_w^T
static constexpr size_t OFF_W2    = OFF_W1    + (size_t)2048 * 512 * 2;   // mlp_w1^T
static constexpr size_t OFF_H     = OFF_W2    + (size_t)512 * 2048 * 2;   // mlp_w2^T end
static constexpr size_t OFF_QKV   = OFF_H     + (size_t)65536 * 512 * 2;  // LN out (reused for LN2 out)
static constexpr size_t OFF_ATTN  = OFF_QKV   + (size_t)65536 * 1536 * 2; // qkv rows (windowed order)
static constexpr size_t OFF_M     = OFF_QKV;  // MLP intermediate reuses qkv+attn region (same size)
// total = OFF_ATTN + 65536*512*2 = ~326 MiB

// ---------------- weight prep: fp32 (K,N) -> bf16 (N,K) ----------------
__global__ __launch_bounds__(256) void wprep_kernel(
    const float* __restrict__ W, BF16* __restrict__ Wt, int K, int N) {
  __shared__ float t[64][65];
  const int n0 = blockIdx.x * 64, k0 = blockIdx.y * 64;
  const int tid = threadIdx.x;
#pragma unroll
  for (int it = 0; it < 16; ++it) {
    int idx = it * 256 + tid;
    int r = idx >> 6, c = idx & 63;
    t[r][c] = W[(size_t)(k0 + r) * N + (n0 + c)];
  }
  __syncthreads();
#pragma unroll
  for (int it = 0; it < 16; ++it) {
    int idx = it * 256 + tid;
    int r = idx >> 6, c = idx & 63;
    Wt[(size_t)(n0 + r) * K + (k0 + c)] = __float2bfloat16(t[c][r]);
  }
}

// ---------------- LayerNorm (fp32 in, bf16 out), one wave per row ----------------
__global__ __launch_bounds__(256) void ln_kernel(
    const float* __restrict__ x, const float* __restrict__ w,
    const float* __restrict__ b, BF16* __restrict__ out) {
  const int lane = threadIdx.x & 63;
  const size_t row = (size_t)blockIdx.x * 4 + (threadIdx.x >> 6);
  const float* xr = x + row * 512 + lane * 8;
  float xv[8], wv[8], bv[8];
  *(float4*)&xv[0] = *(const float4*)xr;
  *(float4*)&xv[4] = *(const float4*)(xr + 4);
  *(float4*)&wv[0] = *(const float4*)(w + lane * 8);
  *(float4*)&wv[4] = *(const float4*)(w + lane * 8 + 4);
  *(float4*)&bv[0] = *(const float4*)(b + lane * 8);
  *(float4*)&bv[4] = *(const float4*)(b + lane * 8 + 4);
  float s = 0.0f, ss = 0.0f;
#pragma unroll
  for (int t = 0; t < 8; ++t) { s += xv[t]; ss += xv[t] * xv[t]; }
#pragma unroll
  for (int o = 32; o > 0; o >>= 1) { s += __shfl_xor(s, o); ss += __shfl_xor(ss, o); }
  const float mu = s * (1.0f / 512.0f);
  const float var = ss * (1.0f / 512.0f) - mu * mu;
  const float rs = rsqrtf(var + 1e-5f);
  BF16 ob[8];
#pragma unroll
  for (int t = 0; t < 8; ++t)
    ob[t] = __float2bfloat16((xv[t] - mu) * rs * wv[t] + bv[t]);
  *(uint4*)(out + row * 512 + lane * 8) = *(const uint4*)ob;
}

// ---------------- GEMM (A bf16 row-gatherable, Bt = (Nout,K) bf16) ----------------
__device__ __forceinline__ void gload16(const BF16* g, BF16* l) {
  __builtin_amdgcn_global_load_lds(
      (const __attribute__((address_space(1))) void*)g,
      (__attribute__((address_space(3))) void*)l, 16, 0, 0);
}

// windowed GEMM row r -> natural source row (roll -4 + repo's window_partition)
__device__ __forceinline__ int win_src_row(int r) {
  const int b = r >> 12;
  const int s = (r >> 9) & 7;
  const int mm = (r >> 3) & 63;
  const int j = r & 7;
  const int p = (64 * mm + 8 * j + s + 4) & 4095;
  return (b << 12) + p;
}

// EPI: 0 = +bias -> bf16 store; 1 = +bias -> GELU -> bf16 store;
//      2 = +bias, window-reverse+roll scatter, += residual, f32 store;
//      3 = +bias, outf[r*512+col] += v (in-place residual, f32)
template <int ROWMAP, int EPI>
__global__ __launch_bounds__(256) void gemm_k(
    const BF16* __restrict__ A, const BF16* __restrict__ Bt,
    const float* __restrict__ bias, const float* __restrict__ resid,
    float* __restrict__ outf, BF16* __restrict__ outb,
    int K, int Nout) {
  __shared__ __align__(16) BF16 As[128 * 32];
  __shared__ __align__(16) BF16 Bs[128 * 32];

  const int tid = threadIdx.x;
  const int lane = tid & 63;
  const int wv = tid >> 6;
  const int wr = wv >> 1, wc = wv & 1;
  const int bn = blockIdx.x, bm = blockIdx.y;  // x = N-tile (A-tile reuse between adjacent blocks)
  const int row0 = bm * 128, col0 = bn * 128;

  const int sub = lane >> 2;        // row within 16-row chunk
  const int cg8 = (lane & 3) * 8;   // bf16 col offset within BK=32

  const int trA0 = wv * 16 + sub;
  const int trA1 = (wv + 4) * 16 + sub;
  int garow0 = row0 + trA0, garow1 = row0 + trA1;
  if (ROWMAP == 1) { garow0 = win_src_row(garow0); garow1 = win_src_row(garow1); }
  const BF16* pA0 = A + (size_t)garow0 * K + cg8;
  const BF16* pA1 = A + (size_t)garow1 * K + cg8;
  const BF16* pB0 = Bt + (size_t)(col0 + trA0) * K + cg8;
  const BF16* pB1 = Bt + (size_t)(col0 + trA1) * K + cg8;

  BF16* lA0 = &As[wv * 512];
  BF16* lA1 = &As[(wv + 4) * 512];
  BF16* lB0 = &Bs[wv * 512];
  BF16* lB1 = &Bs[(wv + 4) * 512];

  floatx4 acc[4][4];
#pragma unroll
  for (int m = 0; m < 4; ++m)
#pragma unroll
    for (int n = 0; n < 4; ++n) acc[m][n] = floatx4{0.f, 0.f, 0.f, 0.f};

  const int g8 = (lane >> 4) * 8;
  const int r16 = lane & 15;

  for (int kk = 0; kk < K; kk += 32) {
    gload16(pA0 + kk, lA0);
    gload16(pA1 + kk, lA1);
    gload16(pB0 + kk, lB0);
    gload16(pB1 + kk, lB1);
    asm volatile("s_waitcnt vmcnt(0)" ::: "memory");
    __syncthreads();
    bf16x8 fa[4], fb[4];
#pragma unroll
    for (int m = 0; m < 4; ++m)
      fa[m] = *(const bf16x8*)&As[(wr * 64 + m * 16 + r16) * 32 + g8];
#pragma unroll
    for (int n = 0; n < 4; ++n)
      fb[n] = *(const bf16x8*)&Bs[(wc * 64 + n * 16 + r16) * 32 + g8];
#pragma unroll
    for (int m = 0; m < 4; ++m)
#pragma unroll
      for (int n = 0; n < 4; ++n)
        acc[m][n] = __builtin_amdgcn_mfma_f32_16x16x32_bf16(fa[m], fb[n], acc[m][n], 0, 0, 0);
    __syncthreads();
  }

  float bsv[4];
#pragma unroll
  for (int n = 0; n < 4; ++n) bsv[n] = bias[col0 + wc * 64 + n * 16 + r16];

#pragma unroll
  for (int m = 0; m < 4; ++m) {
    const int rbase = row0 + wr * 64 + m * 16 + (lane >> 4) * 4;
#pragma unroll
    for (int n = 0; n < 4; ++n) {
      const int col = col0 + wc * 64 + n * 16 + r16;
#pragma unroll
      for (int e = 0; e < 4; ++e) {
        const int r = rbase + e;
        float v = acc[m][n][e] + bsv[n];
        if (EPI == 0) {
          outb[(size_t)r * Nout + col] = __float2bfloat16(v);
        } else if (EPI == 1) {
          float gv = 0.5f * v * (1.0f + erff(v * 0.70710678118654752f));
          outb[(size_t)r * Nout + col] = __float2bfloat16(gv);
        } else if (EPI == 2) {
          // window_reverse (non-inverse of partition!) + roll(+4) + residual
          const int b = r >> 12;
          const int np = (r >> 3) & 511;
          const int ap = r & 7;
          const int io = ((ap << 9) + np + 4) & 4095;
          const size_t o = ((size_t)(b << 12) + io) * 512 + col;
          outf[o] = resid[o] + v;
        } else {
          const size_t o = (size_t)r * 512 + col;
          outf[o] += v;
        }
      }
    }
  }
}

// ---------------- per-window attention (WS=8, H=8, HD=64) ----------------
__global__ __launch_bounds__(64) void attn_kernel(
    const BF16* __restrict__ qkv, BF16* __restrict__ out) {
  const int w = blockIdx.x;       // global window id (b*512 + s*64 + m)
  const int lane = threadIdx.x;
  const int qi = lane >> 3, kj = lane & 7;
  __shared__ __align__(16) BF16 sm[8 * 1544];  // 8 rows x 1536 (+8 pad to dodge bank conflicts)
  const BF16* src = qkv + (size_t)w * 8 * 1536;
#pragma unroll
  for (int rr = 0; rr < 8; ++rr) {
    const uint4* s4 = (const uint4*)(src + (size_t)rr * 1536);
    uint4* d4 = (uint4*)(&sm[rr * 1544]);
#pragma unroll
    for (int c = 0; c < 3; ++c) d4[c * 64 + lane] = s4[c * 64 + lane];
  }
  __syncthreads();

  // mask from rolled positions; regions: [0,4088)=0, [4088,4092)=1, [4092,4096)=2
  const int s = (w >> 6) & 7, mm = w & 63;
  const int pi = 64 * mm + 8 * qi + s;
  const int pj = 64 * mm + 8 * kj + s;
  const int ri = pi >= 4092 ? 2 : (pi >= 4088 ? 1 : 0);
  const int rj = pj >= 4092 ? 2 : (pj >= 4088 ? 1 : 0);
  const float maskv = (ri != rj) ? -100.0f : 0.0f;

  for (int h = 0; h < 8; ++h) {
    const BF16* qp = &sm[qi * 1544 + h * 64];
    const BF16* kp = &sm[kj * 1544 + 512 + h * 64];
    float acc = 0.0f;
#pragma unroll
    for (int d0 = 0; d0 < 8; ++d0) {
      bf16x8 qv = *(const bf16x8*)(qp + d0 * 8);
      bf16x8 kv = *(const bf16x8*)(kp + d0 * 8);
#pragma unroll
      for (int t = 0; t < 8; ++t) acc += (float)qv[t] * (float)kv[t];
    }
    float sc = acc * 0.125f + maskv;
    float mx = sc;
    mx = fmaxf(mx, __shfl_xor(mx, 1, 8));
    mx = fmaxf(mx, __shfl_xor(mx, 2, 8));
    mx = fmaxf(mx, __shfl_xor(mx, 4, 8));
    float e = __expf(sc - mx);
    float den = e;
    den += __shfl_xor(den, 1, 8);
    den += __shfl_xor(den, 2, 8);
    den += __shfl_xor(den, 4, 8);
    const float P = e / den;

    float o8[8];
#pragma unroll
    for (int t = 0; t < 8; ++t) o8[t] = 0.0f;
#pragma unroll
    for (int j2 = 0; j2 < 8; ++j2) {
      float p2 = __shfl(P, j2, 8);
      bf16x8 vv = *(const bf16x8*)(&sm[j2 * 1544 + 1024 + h * 64 + kj * 8]);
#pragma unroll
      for (int t = 0; t < 8; ++t) o8[t] += p2 * (float)vv[t];
    }
    BF16 ob[8];
#pragma unroll
    for (int t = 0; t < 8; ++t) ob[t] = __float2bfloat16(o8[t]);
    *(uint4*)(&out[((size_t)w * 8 + qi) * 512 + h * 64 + kj * 8]) = *(const uint4*)ob;
  }
}

// ---------------- launch ----------------
extern "C" void kernel_launch(void* const* d_in, const int* in_sizes, int n_in,
                              void* d_out, int out_size, void* d_ws, size_t ws_size,
                              hipStream_t stream) {
  (void)in_sizes; (void)n_in; (void)out_size; (void)ws_size;
  const float* x     = (const float*)d_in[0];
  const float* n1w   = (const float*)d_in[1];
  const float* n1b   = (const float*)d_in[2];
  const float* qkvw  = (const float*)d_in[3];
  const float* qkvb  = (const float*)d_in[4];
  const float* projw = (const float*)d_in[5];
  const float* projb = (const float*)d_in[6];
  const float* n2w   = (const float*)d_in[7];
  const float* n2b   = (const float*)d_in[8];
  const float* w1    = (const float*)d_in[9];
  const float* b1    = (const float*)d_in[10];
  const float* w2    = (const float*)d_in[11];
  const float* b2    = (const float*)d_in[12];
  float* out = (float*)d_out;
  char* ws = (char*)d_ws;

  BF16* wt_qkv  = (BF16*)(ws + OFF_WQKV);
  BF16* wt_proj = (BF16*)(ws + OFF_WPROJ);
  BF16* wt_w1   = (BF16*)(ws + OFF_W1);
  BF16* wt_w2   = (BF16*)(ws + OFF_W2);
  BF16* hbuf    = (BF16*)(ws + OFF_H);
  BF16* qkvbuf  = (BF16*)(ws + OFF_QKV);
  BF16* attnbuf = (BF16*)(ws + OFF_ATTN);
  BF16* mbuf    = (BF16*)(ws + OFF_M);

  // weights -> bf16 transposed (Nout, K)
  wprep_kernel<<<dim3(24, 8), 256, 0, stream>>>(qkvw, wt_qkv, 512, 1536);
  wprep_kernel<<<dim3(8, 8), 256, 0, stream>>>(projw, wt_proj, 512, 512);
  wprep_kernel<<<dim3(32, 8), 256, 0, stream>>>(w1, wt_w1, 512, 2048);
  wprep_kernel<<<dim3(8, 32), 256, 0, stream>>>(w2, wt_w2, 2048, 512);

  // LN1 -> h (bf16, natural order)
  ln_kernel<<<16384, 256, 0, stream>>>(x, n1w, n1b, hbuf);
  // qkv = gather(h) @ qkv_w + qkv_b   (rows in windowed order)
  gemm_k<1, 0><<<dim3(12, 512), 256, 0, stream>>>(hbuf, wt_qkv, qkvb, nullptr, nullptr, qkvbuf, 512, 1536);
  // per-window masked attention
  attn_kernel<<<8192, 64, 0, stream>>>(qkvbuf, attnbuf);
  // proj + window-reverse + roll + residual -> x2 (fp32, in d_out)
  gemm_k<0, 2><<<dim3(4, 512), 256, 0, stream>>>(attnbuf, wt_proj, projb, x, out, nullptr, 512, 512);
  // LN2(x2) -> h2 (bf16, reuse hbuf)
  ln_kernel<<<16384, 256, 0, stream>>>(out, n2w, n2b, hbuf);
  // MLP1 + exact GELU -> m (bf16)
  gemm_k<0, 1><<<dim3(16, 512), 256, 0, stream>>>(hbuf, wt_w1, b1, nullptr, nullptr, mbuf, 512, 2048);
  // MLP2 + in-place residual into d_out
  gemm_k<0, 3><<<dim3(4, 512), 256, 0, stream>>>(mbuf, wt_w2, b2, nullptr, out, nullptr, 2048, 512);
}

// Round 2
// 920.827 us; speedup vs baseline: 1.0171x; 1.0171x over previous
//
#include <hip/hip_runtime.h>
#include <hip/hip_bf16.h>
#include <cstdint>
#include <cstddef>

typedef __hip_bfloat16 BF16;
typedef __bf16 bf16x8 __attribute__((ext_vector_type(8)));
typedef float floatx4 __attribute__((ext_vector_type(4)));

// ---------------- workspace layout (bytes) ----------------
static constexpr size_t OFF_WQKV  = 0;
static constexpr size_t OFF_WPROJ = OFF_WQKV  + (size_t)1536 * 512 * 2;   // qkv_w^T bf16
static constexpr size_t OFF_W1    = OFF_WPROJ + (size_t)512 * 512 * 2;    // proj_w^T
static constexpr size_t OFF_W2    = OFF_W1    + (size_t)2048 * 512 * 2;   // mlp_w1^T
static constexpr size_t OFF_H     = OFF_W2    + (size_t)512 * 2048 * 2;   // mlp_w2^T end
static constexpr size_t OFF_QKV   = OFF_H     + (size_t)65536 * 512 * 2;  // LN out (reused for LN2 out)
static constexpr size_t OFF_ATTN  = OFF_QKV   + (size_t)65536 * 1536 * 2; // qkv rows (windowed order)
static constexpr size_t OFF_M     = OFF_QKV;  // MLP intermediate reuses qkv+attn region

// ---------------- weight prep: fp32 (K,N) -> bf16 (N,K) ----------------
__global__ __launch_bounds__(256) void wprep_kernel(
    const float* __restrict__ W, BF16* __restrict__ Wt, int K, int N) {
  __shared__ float t[64][65];
  const int n0 = blockIdx.x * 64, k0 = blockIdx.y * 64;
  const int tid = threadIdx.x;
#pragma unroll
  for (int it = 0; it < 16; ++it) {
    int idx = it * 256 + tid;
    int r = idx >> 6, c = idx & 63;
    t[r][c] = W[(size_t)(k0 + r) * N + (n0 + c)];
  }
  __syncthreads();
#pragma unroll
  for (int it = 0; it < 16; ++it) {
    int idx = it * 256 + tid;
    int r = idx >> 6, c = idx & 63;
    Wt[(size_t)(n0 + r) * K + (k0 + c)] = __float2bfloat16(t[c][r]);
  }
}

// ---------------- LayerNorm (fp32 in, bf16 out), one wave per row ----------------
__global__ __launch_bounds__(256) void ln_kernel(
    const float* __restrict__ x, const float* __restrict__ w,
    const float* __restrict__ b, BF16* __restrict__ out) {
  const int lane = threadIdx.x & 63;
  const size_t row = (size_t)blockIdx.x * 4 + (threadIdx.x >> 6);
  const float* xr = x + row * 512 + lane * 8;
  float xv[8], wv[8], bv[8];
  *(float4*)&xv[0] = *(const float4*)xr;
  *(float4*)&xv[4] = *(const float4*)(xr + 4);
  *(float4*)&wv[0] = *(const float4*)(w + lane * 8);
  *(float4*)&wv[4] = *(const float4*)(w + lane * 8 + 4);
  *(float4*)&bv[0] = *(const float4*)(b + lane * 8);
  *(float4*)&bv[4] = *(const float4*)(b + lane * 8 + 4);
  float s = 0.0f, ss = 0.0f;
#pragma unroll
  for (int t = 0; t < 8; ++t) { s += xv[t]; ss += xv[t] * xv[t]; }
#pragma unroll
  for (int o = 32; o > 0; o >>= 1) { s += __shfl_xor(s, o); ss += __shfl_xor(ss, o); }
  const float mu = s * (1.0f / 512.0f);
  const float var = ss * (1.0f / 512.0f) - mu * mu;
  const float rs = rsqrtf(var + 1e-5f);
  BF16 ob[8];
#pragma unroll
  for (int t = 0; t < 8; ++t)
    ob[t] = __float2bfloat16((xv[t] - mu) * rs * wv[t] + bv[t]);
  *(uint4*)(out + row * 512 + lane * 8) = *(const uint4*)ob;
}

// ---------------- helpers ----------------
__device__ __forceinline__ void gload16(const BF16* g, BF16* l) {
  __builtin_amdgcn_global_load_lds(
      (const __attribute__((address_space(1))) void*)g,
      (__attribute__((address_space(3))) void*)l, 16, 0, 0);
}

// windowed GEMM row r -> natural source row (roll -4 + repo's window_partition)
__device__ __forceinline__ int win_src_row(int r) {
  const int b = r >> 12;
  const int s = (r >> 9) & 7;
  const int mm = (r >> 3) & 63;
  const int j = r & 7;
  const int p = (64 * mm + 8 * j + s + 4) & 4095;
  return (b << 12) + p;
}

// exact GELU via Abramowitz-Stegun 7.1.26 erf (|eps| <= 1.5e-7), ~14 VALU ops
__device__ __forceinline__ float fast_gelu(float v) {
  const float x = fabsf(v) * 0.70710678118654752f;
  const float t = __builtin_amdgcn_rcpf(1.0f + 0.3275911f * x);
  const float poly = t * (0.254829592f +
                     t * (-0.284496736f +
                     t * (1.421413741f +
                     t * (-1.453152027f +
                     t * 1.061405429f))));
  const float erfc_ = poly * __expf(-x * x);      // = 1 - erf(x), x >= 0
  const float erfv = copysignf(1.0f - erfc_, v);
  return 0.5f * v * (1.0f + erfv);
}

// ---------------- GEMM: 128x128 tile, BK=32, double-buffered 2-phase ----------------
// EPI: 0 = +bias -> bf16; 1 = +bias -> GELU -> bf16;
//      2 = +bias, window-reverse+roll scatter, += residual, f32;
//      3 = +bias, outf[r*512+col] += v (in-place residual, f32)
template <int ROWMAP, int EPI, int K>
__global__ __launch_bounds__(256) void gemm_k(
    const BF16* __restrict__ A, const BF16* __restrict__ Bt,
    const float* __restrict__ bias, const float* __restrict__ resid,
    float* __restrict__ outf, BF16* __restrict__ outb, int Nout) {
  __shared__ __align__(16) BF16 As[2][128 * 32];
  __shared__ __align__(16) BF16 Bs[2][128 * 32];

  const int tid = threadIdx.x;
  const int lane = tid & 63;
  const int wv = tid >> 6;
  const int wr = wv >> 1, wc = wv & 1;

  // T1: chunked XCD swizzle (all grids have nwg % 8 == 0)
  const int gx = gridDim.x;
  const int nwg = gx * gridDim.y;
  const int hwid = blockIdx.y * gx + blockIdx.x;
  const int swz = (hwid & 7) * (nwg >> 3) + (hwid >> 3);
  const int bm = swz / gx, bn = swz - bm * gx;
  const int row0 = bm * 128, col0 = bn * 128;

  const int sub = lane >> 2;        // row within 16-row staging chunk
  const int cg8 = (lane & 3) * 8;   // bf16 col offset within BK=32

  const int trA0 = wv * 16 + sub;
  const int trA1 = (wv + 4) * 16 + sub;
  int garow0 = row0 + trA0, garow1 = row0 + trA1;
  if (ROWMAP == 1) { garow0 = win_src_row(garow0); garow1 = win_src_row(garow1); }
  const BF16* qA0 = A + (size_t)garow0 * K + cg8;
  const BF16* qA1 = A + (size_t)garow1 * K + cg8;
  const BF16* qB0 = Bt + (size_t)(col0 + trA0) * K + cg8;
  const BF16* qB1 = Bt + (size_t)(col0 + trA1) * K + cg8;

  floatx4 acc[4][4];
#pragma unroll
  for (int m = 0; m < 4; ++m)
#pragma unroll
    for (int n = 0; n < 4; ++n) acc[m][n] = floatx4{0.f, 0.f, 0.f, 0.f};

  const int g8 = (lane >> 4) * 8;
  const int r16 = lane & 15;

#define STAGE(bufidx) do {                                   \
    gload16(qA0, &As[bufidx][wv * 512]);                     \
    gload16(qA1, &As[bufidx][(wv + 4) * 512]);               \
    gload16(qB0, &Bs[bufidx][wv * 512]);                     \
    gload16(qB1, &Bs[bufidx][(wv + 4) * 512]);               \
    qA0 += 32; qA1 += 32; qB0 += 32; qB1 += 32;              \
  } while (0)

#define COMPUTE(bufidx) do {                                                   \
    bf16x8 fa[4], fb[4];                                                       \
    _Pragma("unroll")                                                          \
    for (int m = 0; m < 4; ++m)                                                \
      fa[m] = *(const bf16x8*)&As[bufidx][(wr * 64 + m * 16 + r16) * 32 + g8]; \
    _Pragma("unroll")                                                          \
    for (int n = 0; n < 4; ++n)                                                \
      fb[n] = *(const bf16x8*)&Bs[bufidx][(wc * 64 + n * 16 + r16) * 32 + g8]; \
    _Pragma("unroll")                                                          \
    for (int m = 0; m < 4; ++m)                                                \
      _Pragma("unroll")                                                        \
      for (int n = 0; n < 4; ++n)                                              \
        acc[m][n] = __builtin_amdgcn_mfma_f32_16x16x32_bf16(fa[m], fb[n],      \
                                                            acc[m][n], 0, 0, 0); \
  } while (0)

  // prologue: stage tile 0
  STAGE(0);
  __syncthreads();   // drains vmcnt(0) + lgkmcnt(0) per HIP barrier semantics

  constexpr int HALF = K / 64;   // pairs of BK=32 tiles
#pragma unroll 4
  for (int t = 0; t < HALF - 1; ++t) {
    STAGE(1);        // issue next-tile loads BEFORE compute (latency hides under MFMA)
    COMPUTE(0);
    __syncthreads();
    STAGE(0);
    COMPUTE(1);
    __syncthreads();
  }
  STAGE(1);
  COMPUTE(0);
  __syncthreads();
  COMPUTE(1);

#undef STAGE
#undef COMPUTE

  float bsv[4];
#pragma unroll
  for (int n = 0; n < 4; ++n) bsv[n] = bias[col0 + wc * 64 + n * 16 + r16];

#pragma unroll
  for (int m = 0; m < 4; ++m) {
    const int rbase = row0 + wr * 64 + m * 16 + (lane >> 4) * 4;
#pragma unroll
    for (int n = 0; n < 4; ++n) {
      const int col = col0 + wc * 64 + n * 16 + r16;
#pragma unroll
      for (int e = 0; e < 4; ++e) {
        const int r = rbase + e;
        float v = acc[m][n][e] + bsv[n];
        if (EPI == 0) {
          outb[(size_t)r * Nout + col] = __float2bfloat16(v);
        } else if (EPI == 1) {
          outb[(size_t)r * Nout + col] = __float2bfloat16(fast_gelu(v));
        } else if (EPI == 2) {
          // window_reverse (non-inverse of partition!) + roll(+4) + residual
          const int b = r >> 12;
          const int np = (r >> 3) & 511;
          const int ap = r & 7;
          const int io = ((ap << 9) + np + 4) & 4095;
          const size_t o = ((size_t)(b << 12) + io) * 512 + col;
          outf[o] = resid[o] + v;
        } else {
          const size_t o = (size_t)r * 512 + col;
          outf[o] += v;
        }
      }
    }
  }
}

// ---------------- per-window attention (WS=8, H=8, HD=64) ----------------
__global__ __launch_bounds__(64) void attn_kernel(
    const BF16* __restrict__ qkv, BF16* __restrict__ out) {
  const int w = blockIdx.x;       // global window id (b*512 + s*64 + m)
  const int lane = threadIdx.x;
  const int qi = lane >> 3, kj = lane & 7;
  __shared__ __align__(16) BF16 sm[8 * 1544];  // 8 rows x 1536 (+8 pad)
  const BF16* src = qkv + (size_t)w * 8 * 1536;
#pragma unroll
  for (int rr = 0; rr < 8; ++rr) {
    const uint4* s4 = (const uint4*)(src + (size_t)rr * 1536);
    uint4* d4 = (uint4*)(&sm[rr * 1544]);
#pragma unroll
    for (int c = 0; c < 3; ++c) d4[c * 64 + lane] = s4[c * 64 + lane];
  }
  __syncthreads();

  // mask from rolled positions; regions: [0,4088)=0, [4088,4092)=1, [4092,4096)=2
  const int s = (w >> 6) & 7, mm = w & 63;
  const int pi = 64 * mm + 8 * qi + s;
  const int pj = 64 * mm + 8 * kj + s;
  const int ri = pi >= 4092 ? 2 : (pi >= 4088 ? 1 : 0);
  const int rj = pj >= 4092 ? 2 : (pj >= 4088 ? 1 : 0);
  const float maskv = (ri != rj) ? -100.0f : 0.0f;

  for (int h = 0; h < 8; ++h) {
    const BF16* qp = &sm[qi * 1544 + h * 64];
    const BF16* kp = &sm[kj * 1544 + 512 + h * 64];
    float acc = 0.0f;
#pragma unroll
    for (int d0 = 0; d0 < 8; ++d0) {
      bf16x8 qv = *(const bf16x8*)(qp + d0 * 8);
      bf16x8 kv = *(const bf16x8*)(kp + d0 * 8);
#pragma unroll
      for (int t = 0; t < 8; ++t) acc += (float)qv[t] * (float)kv[t];
    }
    float sc = acc * 0.125f + maskv;
    float mx = sc;
    mx = fmaxf(mx, __shfl_xor(mx, 1, 8));
    mx = fmaxf(mx, __shfl_xor(mx, 2, 8));
    mx = fmaxf(mx, __shfl_xor(mx, 4, 8));
    float e = __expf(sc - mx);
    float den = e;
    den += __shfl_xor(den, 1, 8);
    den += __shfl_xor(den, 2, 8);
    den += __shfl_xor(den, 4, 8);
    const float P = e / den;

    float o8[8];
#pragma unroll
    for (int t = 0; t < 8; ++t) o8[t] = 0.0f;
#pragma unroll
    for (int j2 = 0; j2 < 8; ++j2) {
      float p2 = __shfl(P, j2, 8);
      bf16x8 vv = *(const bf16x8*)(&sm[j2 * 1544 + 1024 + h * 64 + kj * 8]);
#pragma unroll
      for (int t = 0; t < 8; ++t) o8[t] += p2 * (float)vv[t];
    }
    BF16 ob[8];
#pragma unroll
    for (int t = 0; t < 8; ++t) ob[t] = __float2bfloat16(o8[t]);
    *(uint4*)(&out[((size_t)w * 8 + qi) * 512 + h * 64 + kj * 8]) = *(const uint4*)ob;
  }
}

// ---------------- launch ----------------
extern "C" void kernel_launch(void* const* d_in, const int* in_sizes, int n_in,
                              void* d_out, int out_size, void* d_ws, size_t ws_size,
                              hipStream_t stream) {
  (void)in_sizes; (void)n_in; (void)out_size; (void)ws_size;
  const float* x     = (const float*)d_in[0];
  const float* n1w   = (const float*)d_in[1];
  const float* n1b   = (const float*)d_in[2];
  const float* qkvw  = (const float*)d_in[3];
  const float* qkvb  = (const float*)d_in[4];
  const float* projw = (const float*)d_in[5];
  const float* projb = (const float*)d_in[6];
  const float* n2w   = (const float*)d_in[7];
  const float* n2b   = (const float*)d_in[8];
  const float* w1    = (const float*)d_in[9];
  const float* b1    = (const float*)d_in[10];
  const float* w2    = (const float*)d_in[11];
  const float* b2    = (const float*)d_in[12];
  float* out = (float*)d_out;
  char* ws = (char*)d_ws;

  BF16* wt_qkv  = (BF16*)(ws + OFF_WQKV);
  BF16* wt_proj = (BF16*)(ws + OFF_WPROJ);
  BF16* wt_w1   = (BF16*)(ws + OFF_W1);
  BF16* wt_w2   = (BF16*)(ws + OFF_W2);
  BF16* hbuf    = (BF16*)(ws + OFF_H);
  BF16* qkvbuf  = (BF16*)(ws + OFF_QKV);
  BF16* attnbuf = (BF16*)(ws + OFF_ATTN);
  BF16* mbuf    = (BF16*)(ws + OFF_M);

  // weights -> bf16 transposed (Nout, K)
  wprep_kernel<<<dim3(24, 8), 256, 0, stream>>>(qkvw, wt_qkv, 512, 1536);
  wprep_kernel<<<dim3(8, 8), 256, 0, stream>>>(projw, wt_proj, 512, 512);
  wprep_kernel<<<dim3(32, 8), 256, 0, stream>>>(w1, wt_w1, 512, 2048);
  wprep_kernel<<<dim3(8, 32), 256, 0, stream>>>(w2, wt_w2, 2048, 512);

  // LN1 -> h (bf16, natural order)
  ln_kernel<<<16384, 256, 0, stream>>>(x, n1w, n1b, hbuf);
  // qkv = gather(h) @ qkv_w + qkv_b   (rows in windowed order)
  gemm_k<1, 0, 512><<<dim3(12, 512), 256, 0, stream>>>(hbuf, wt_qkv, qkvb, nullptr, nullptr, qkvbuf, 1536);
  // per-window masked attention
  attn_kernel<<<8192, 64, 0, stream>>>(qkvbuf, attnbuf);
  // proj + window-reverse + roll + residual -> x2 (fp32, in d_out)
  gemm_k<0, 2, 512><<<dim3(4, 512), 256, 0, stream>>>(attnbuf, wt_proj, projb, x, out, nullptr, 512);
  // LN2(x2) -> h2 (bf16, reuse hbuf)
  ln_kernel<<<16384, 256, 0, stream>>>(out, n2w, n2b, hbuf);
  // MLP1 + exact GELU -> m (bf16)
  gemm_k<0, 1, 512><<<dim3(16, 512), 256, 0, stream>>>(hbuf, wt_w1, b1, nullptr, nullptr, mbuf, 2048);
  // MLP2 + in-place residual into d_out
  gemm_k<0, 3, 2048><<<dim3(4, 512), 256, 0, stream>>>(mbuf, wt_w2, b2, nullptr, out, nullptr, 512);
}

// Round 3
// 699.066 us; speedup vs baseline: 1.3398x; 1.3172x over previous
//
#include <hip/hip_runtime.h>
#include <hip/hip_bf16.h>
#include <cstdint>
#include <cstddef>

typedef __hip_bfloat16 BF16;
typedef __bf16 bf16x8 __attribute__((ext_vector_type(8)));
typedef float floatx4 __attribute__((ext_vector_type(4)));

// ---------------- workspace layout (bytes) ----------------
static constexpr size_t OFF_WQKV  = 0;
static constexpr size_t OFF_WPROJ = OFF_WQKV  + (size_t)1536 * 512 * 2;
static constexpr size_t OFF_W1    = OFF_WPROJ + (size_t)512 * 512 * 2;
static constexpr size_t OFF_W2    = OFF_W1    + (size_t)2048 * 512 * 2;
static constexpr size_t OFF_H     = OFF_W2    + (size_t)512 * 2048 * 2;
static constexpr size_t OFF_QKV   = OFF_H     + (size_t)65536 * 512 * 2;
static constexpr size_t OFF_ATTN  = OFF_QKV   + (size_t)65536 * 1536 * 2;
static constexpr size_t OFF_M     = OFF_QKV;   // MLP intermediate reuses qkv+attn region

// ---------------- weight prep: fp32 (K,N) -> bf16 (N,K) ----------------
__global__ __launch_bounds__(256) void wprep_kernel(
    const float* __restrict__ W, BF16* __restrict__ Wt, int K, int N) {
  __shared__ float t[64][65];
  const int n0 = blockIdx.x * 64, k0 = blockIdx.y * 64;
  const int tid = threadIdx.x;
#pragma unroll
  for (int it = 0; it < 16; ++it) {
    int idx = it * 256 + tid;
    int r = idx >> 6, c = idx & 63;
    t[r][c] = W[(size_t)(k0 + r) * N + (n0 + c)];
  }
  __syncthreads();
#pragma unroll
  for (int it = 0; it < 16; ++it) {
    int idx = it * 256 + tid;
    int r = idx >> 6, c = idx & 63;
    Wt[(size_t)(n0 + r) * K + (k0 + c)] = __float2bfloat16(t[c][r]);
  }
}

// ---------------- LayerNorm (fp32 in, bf16 out), one wave per row ----------------
__global__ __launch_bounds__(256) void ln_kernel(
    const float* __restrict__ x, const float* __restrict__ w,
    const float* __restrict__ b, BF16* __restrict__ out) {
  const int lane = threadIdx.x & 63;
  const size_t row = (size_t)blockIdx.x * 4 + (threadIdx.x >> 6);
  const float* xr = x + row * 512 + lane * 8;
  float xv[8], wv[8], bv[8];
  *(float4*)&xv[0] = *(const float4*)xr;
  *(float4*)&xv[4] = *(const float4*)(xr + 4);
  *(float4*)&wv[0] = *(const float4*)(w + lane * 8);
  *(float4*)&wv[4] = *(const float4*)(w + lane * 8 + 4);
  *(float4*)&bv[0] = *(const float4*)(b + lane * 8);
  *(float4*)&bv[4] = *(const float4*)(b + lane * 8 + 4);
  float s = 0.0f, ss = 0.0f;
#pragma unroll
  for (int t = 0; t < 8; ++t) { s += xv[t]; ss += xv[t] * xv[t]; }
#pragma unroll
  for (int o = 32; o > 0; o >>= 1) { s += __shfl_xor(s, o); ss += __shfl_xor(ss, o); }
  const float mu = s * (1.0f / 512.0f);
  const float var = ss * (1.0f / 512.0f) - mu * mu;
  const float rs = rsqrtf(var + 1e-5f);
  BF16 ob[8];
#pragma unroll
  for (int t = 0; t < 8; ++t)
    ob[t] = __float2bfloat16((xv[t] - mu) * rs * wv[t] + bv[t]);
  *(uint4*)(out + row * 512 + lane * 8) = *(const uint4*)ob;
}

// ---------------- helpers ----------------
__device__ __forceinline__ void gload16(const BF16* g, const char* l) {
  __builtin_amdgcn_global_load_lds(
      (const __attribute__((address_space(1))) void*)g,
      (__attribute__((address_space(3))) void*)l, 16, 0, 0);
}

__device__ __forceinline__ int win_src_row(int r) {
  const int b = r >> 12;
  const int s = (r >> 9) & 7;
  const int mm = (r >> 3) & 63;
  const int j = r & 7;
  const int p = (64 * mm + 8 * j + s + 4) & 4095;
  return (b << 12) + p;
}

// exact GELU via A&S 7.1.26 erf (|eps| <= 1.5e-7)
__device__ __forceinline__ float fast_gelu(float v) {
  const float x = fabsf(v) * 0.70710678118654752f;
  const float t = __builtin_amdgcn_rcpf(1.0f + 0.3275911f * x);
  const float poly = t * (0.254829592f +
                     t * (-0.284496736f +
                     t * (1.421413741f +
                     t * (-1.453152027f +
                     t * 1.061405429f))));
  const float erfc_ = poly * __expf(-x * x);
  const float erfv = copysignf(1.0f - erfc_, v);
  return 0.5f * v * (1.0f + erfv);
}

// ================= 256x256 8-phase GEMM (T1+T2+T3+T4+T5) =================
// 8 waves as 2(M)x4(N); wave (wm,wn) owns rows {mh*128+wm*64+0..63} for mh=0,1
// and cols {nh*128+wn*32+0..31} for nh=0,1. Phase (mh,nh) touches only A-half mh,
// B-half nh. LDS: dbuf d (64KB each): A-half mh @ d*65536+mh*16384,
// B-half nh @ d*65536+32768+nh*16384. Half = [128 rows][64 K] bf16, 128B/row,
// XOR-swizzled: physical 16B-slot u holds logical slot u^(row&7).
#define GATE4 asm volatile("s_waitcnt vmcnt(4)" ::: "memory")
#define GATE2 asm volatile("s_waitcnt vmcnt(2)" ::: "memory")
#define GATE0 asm volatile("s_waitcnt vmcnt(0)" ::: "memory")
#define GATEN asm volatile("" ::: "memory")
#define BAR() __builtin_amdgcn_s_barrier()
#define WAITL() asm volatile("s_waitcnt lgkmcnt(0)" ::: "memory")

template <int ROWMAP, int EPI, int K>
__global__ __launch_bounds__(512, 2) void gemm256(
    const BF16* __restrict__ A, const BF16* __restrict__ Bt,
    const float* __restrict__ bias, const float* __restrict__ resid,
    float* __restrict__ outf, BF16* __restrict__ outb, int Nout) {
  __shared__ __align__(16) char smem[131072];
  const int tid = threadIdx.x, lane = tid & 63, wv = tid >> 6;
  const int wm = wv >> 2, wn = wv & 3;

  // T1: chunked XCD swizzle (nwg % 8 == 0 for all our grids)
  const int gx = gridDim.x;
  const int nwg = gx * gridDim.y;
  const int hwid = blockIdx.y * gx + blockIdx.x;
  const int swz = (hwid & 7) * (nwg >> 3) + (hwid >> 3);
  const int bm = swz / gx, bn = swz - bm * gx;
  const int row0 = bm * 256, col0 = bn * 256;

  // staging addressing: lane covers (row = c*64 + wv*8 + srow, 16B slot = lane&7)
  // pre-swizzled global source: k-slot = (lane&7) ^ srow
  const int srow = lane >> 3;
  const int scol = ((lane & 7) ^ srow) * 8;
  const BF16* Pa[2][2];
  const BF16* Pb[2][2];
#pragma unroll
  for (int mh = 0; mh < 2; ++mh)
#pragma unroll
    for (int c = 0; c < 2; ++c) {
      int ra = row0 + mh * 128 + c * 64 + wv * 8 + srow;
      if (ROWMAP == 1) ra = win_src_row(ra);
      Pa[mh][c] = A + (size_t)ra * K + scol;
      const int rb = col0 + mh * 128 + c * 64 + wv * 8 + srow;
      Pb[mh][c] = Bt + (size_t)rb * K + scol;
    }
  const int ldsw = wv * 1024;

  // fragment read offsets (swizzled): slot s = ks*4 + (lane>>4), phys = s^(r16&7)
  const int r16 = lane & 15;
  const int sx0 = (((lane >> 4) + 0) ^ (r16 & 7)) * 16;
  const int sx1 = (((lane >> 4) + 4) ^ (r16 & 7)) * 16;
  const int raby = (wm * 64 + r16) * 128;  // + m2*2048 + mh*16384
  const int rbby = (wn * 32 + r16) * 128;  // + n2*2048 + nh*16384

  floatx4 acc[2][4][2][2];
#pragma unroll
  for (int mh = 0; mh < 2; ++mh)
#pragma unroll
    for (int m2 = 0; m2 < 4; ++m2)
#pragma unroll
      for (int nh = 0; nh < 2; ++nh)
#pragma unroll
        for (int n2 = 0; n2 < 2; ++n2)
          acc[mh][m2][nh][n2] = floatx4{0.f, 0.f, 0.f, 0.f};

  bf16x8 fa[4][2], fb0[2][2], fb1[2][2];

#define STG_A(half, dd) do {                                              \
    gload16(Pa[half][0], smem + (dd)*65536 + (half)*16384 + ldsw);        \
    gload16(Pa[half][1], smem + (dd)*65536 + (half)*16384 + 8192 + ldsw); \
  } while (0)
#define STG_B(half, dd) do {                                                      \
    gload16(Pb[half][0], smem + (dd)*65536 + 32768 + (half)*16384 + ldsw);        \
    gload16(Pb[half][1], smem + (dd)*65536 + 32768 + (half)*16384 + 8192 + ldsw); \
  } while (0)
#define ADV() do {                                          \
    Pa[0][0] += 64; Pa[0][1] += 64; Pa[1][0] += 64; Pa[1][1] += 64; \
    Pb[0][0] += 64; Pb[0][1] += 64; Pb[1][0] += 64; Pb[1][1] += 64; \
  } while (0)

#define RD_FA(mh, dd)                                                          \
  _Pragma("unroll")                                                            \
  for (int m2 = 0; m2 < 4; ++m2) {                                             \
    fa[m2][0] = *(const bf16x8*)(smem + (dd)*65536 + (mh)*16384 + raby + m2*2048 + sx0); \
    fa[m2][1] = *(const bf16x8*)(smem + (dd)*65536 + (mh)*16384 + raby + m2*2048 + sx1); \
  }
#define RD_FB(dst, nh, dd)                                                     \
  _Pragma("unroll")                                                            \
  for (int n2 = 0; n2 < 2; ++n2) {                                             \
    dst[n2][0] = *(const bf16x8*)(smem + (dd)*65536 + 32768 + (nh)*16384 + rbby + n2*2048 + sx0); \
    dst[n2][1] = *(const bf16x8*)(smem + (dd)*65536 + 32768 + (nh)*16384 + rbby + n2*2048 + sx1); \
  }
#define MF(mh, nh, fbx)                                                        \
  __builtin_amdgcn_s_setprio(1);                                               \
  _Pragma("unroll")                                                            \
  for (int ks = 0; ks < 2; ++ks)                                               \
    _Pragma("unroll")                                                          \
    for (int m2 = 0; m2 < 4; ++m2)                                             \
      _Pragma("unroll")                                                        \
      for (int n2 = 0; n2 < 2; ++n2)                                           \
        acc[mh][m2][nh][n2] = __builtin_amdgcn_mfma_f32_16x16x32_bf16(         \
            fa[m2][ks], fbx[n2][ks], acc[mh][m2][nh][n2], 0, 0, 0);            \
  __builtin_amdgcn_s_setprio(0)

  // ---------------- prologue: stage K-tile 0 into d0 (order A0,B0,B1,A1) ----
  STG_A(0, 0);
  STG_B(0, 0);
  STG_B(1, 0);
  STG_A(1, 0);
  ADV();
  GATE4;   // A0,B0 landed; B1,A1 in flight
  BAR();

  constexpr int NT = K / 64;
  // ---------------- steady K-tiles 0..NT-2 ----------------
  for (int t = 0; t < NT - 1; ++t) {
    const int dd = t & 1, de = dd ^ 1;
    // phase 0: q(0,0); stage next A0
    RD_FA(0, dd); RD_FB(fb0, 0, dd);
    STG_A(0, de);
    BAR(); WAITL();
    MF(0, 0, fb0);
    GATE4; BAR();
    // phase 1: q(0,1); stage next B0
    RD_FB(fb1, 1, dd);
    STG_B(0, de);
    BAR(); WAITL();
    MF(0, 1, fb1);
    GATE4; BAR();
    // phase 2: q(1,1); stage next B1
    RD_FA(1, dd);
    STG_B(1, de);
    BAR(); WAITL();
    MF(1, 1, fb1);
    GATEN; BAR();
    // phase 3: q(1,0); stage next A1
    STG_A(1, de);
    BAR(); WAITL();
    MF(1, 0, fb0);
    GATE4; BAR();
    ADV();
  }
  // ---------------- tail K-tile NT-1 (no staging; drain 2 -> 0) ------------
  {
    const int dd = (NT - 1) & 1;
    RD_FA(0, dd); RD_FB(fb0, 0, dd);
    BAR(); WAITL();
    MF(0, 0, fb0);
    GATE2; BAR();
    RD_FB(fb1, 1, dd);
    BAR(); WAITL();
    MF(0, 1, fb1);
    GATE0; BAR();
    RD_FA(1, dd);
    BAR(); WAITL();
    MF(1, 1, fb1);
    GATEN; BAR();
    BAR(); WAITL();
    MF(1, 0, fb0);
  }
#undef STG_A
#undef STG_B
#undef ADV
#undef RD_FA
#undef RD_FB
#undef MF

  // ---------------- epilogue ----------------
  float bsv[2][2];
#pragma unroll
  for (int nh = 0; nh < 2; ++nh)
#pragma unroll
    for (int n2 = 0; n2 < 2; ++n2)
      bsv[nh][n2] = bias[col0 + nh * 128 + wn * 32 + n2 * 16 + r16];

#pragma unroll
  for (int mh = 0; mh < 2; ++mh)
#pragma unroll
    for (int m2 = 0; m2 < 4; ++m2) {
      const int rbase = row0 + mh * 128 + wm * 64 + m2 * 16 + (lane >> 4) * 4;
#pragma unroll
      for (int nh = 0; nh < 2; ++nh)
#pragma unroll
        for (int n2 = 0; n2 < 2; ++n2) {
          const int col = col0 + nh * 128 + wn * 32 + n2 * 16 + r16;
#pragma unroll
          for (int e = 0; e < 4; ++e) {
            const int r = rbase + e;
            float v = acc[mh][m2][nh][n2][e] + bsv[nh][n2];
            if (EPI == 0) {
              outb[(size_t)r * Nout + col] = __float2bfloat16(v);
            } else if (EPI == 1) {
              outb[(size_t)r * Nout + col] = __float2bfloat16(fast_gelu(v));
            } else if (EPI == 2) {
              const int b = r >> 12;
              const int np = (r >> 3) & 511;
              const int ap = r & 7;
              const int io = ((ap << 9) + np + 4) & 4095;
              const size_t o = ((size_t)(b << 12) + io) * 512 + col;
              outf[o] = resid[o] + v;
            } else {
              const size_t o = (size_t)r * 512 + col;
              outf[o] += v;
            }
          }
        }
    }
}

// ---------------- per-window attention (WS=8, H=8, HD=64) ----------------
__global__ __launch_bounds__(64) void attn_kernel(
    const BF16* __restrict__ qkv, BF16* __restrict__ out) {
  const int w = blockIdx.x;
  const int lane = threadIdx.x;
  const int qi = lane >> 3, kj = lane & 7;
  __shared__ __align__(16) BF16 sm[8 * 1544];
  const BF16* src = qkv + (size_t)w * 8 * 1536;
#pragma unroll
  for (int rr = 0; rr < 8; ++rr) {
    const uint4* s4 = (const uint4*)(src + (size_t)rr * 1536);
    uint4* d4 = (uint4*)(&sm[rr * 1544]);
#pragma unroll
    for (int c = 0; c < 3; ++c) d4[c * 64 + lane] = s4[c * 64 + lane];
  }
  __syncthreads();

  const int s = (w >> 6) & 7, mm = w & 63;
  const int pi = 64 * mm + 8 * qi + s;
  const int pj = 64 * mm + 8 * kj + s;
  const int ri = pi >= 4092 ? 2 : (pi >= 4088 ? 1 : 0);
  const int rj = pj >= 4092 ? 2 : (pj >= 4088 ? 1 : 0);
  const float maskv = (ri != rj) ? -100.0f : 0.0f;

  for (int h = 0; h < 8; ++h) {
    const BF16* qp = &sm[qi * 1544 + h * 64];
    const BF16* kp = &sm[kj * 1544 + 512 + h * 64];
    float acc = 0.0f;
#pragma unroll
    for (int d0 = 0; d0 < 8; ++d0) {
      bf16x8 qv = *(const bf16x8*)(qp + d0 * 8);
      bf16x8 kv = *(const bf16x8*)(kp + d0 * 8);
#pragma unroll
      for (int t = 0; t < 8; ++t) acc += (float)qv[t] * (float)kv[t];
    }
    float sc = acc * 0.125f + maskv;
    float mx = sc;
    mx = fmaxf(mx, __shfl_xor(mx, 1, 8));
    mx = fmaxf(mx, __shfl_xor(mx, 2, 8));
    mx = fmaxf(mx, __shfl_xor(mx, 4, 8));
    float e = __expf(sc - mx);
    float den = e;
    den += __shfl_xor(den, 1, 8);
    den += __shfl_xor(den, 2, 8);
    den += __shfl_xor(den, 4, 8);
    const float P = e / den;

    float o8[8];
#pragma unroll
    for (int t = 0; t < 8; ++t) o8[t] = 0.0f;
#pragma unroll
    for (int j2 = 0; j2 < 8; ++j2) {
      float p2 = __shfl(P, j2, 8);
      bf16x8 vv = *(const bf16x8*)(&sm[j2 * 1544 + 1024 + h * 64 + kj * 8]);
#pragma unroll
      for (int t = 0; t < 8; ++t) o8[t] += p2 * (float)vv[t];
    }
    BF16 ob[8];
#pragma unroll
    for (int t = 0; t < 8; ++t) ob[t] = __float2bfloat16(o8[t]);
    *(uint4*)(&out[((size_t)w * 8 + qi) * 512 + h * 64 + kj * 8]) = *(const uint4*)ob;
  }
}

// ---------------- launch ----------------
extern "C" void kernel_launch(void* const* d_in, const int* in_sizes, int n_in,
                              void* d_out, int out_size, void* d_ws, size_t ws_size,
                              hipStream_t stream) {
  (void)in_sizes; (void)n_in; (void)out_size; (void)ws_size;
  const float* x     = (const float*)d_in[0];
  const float* n1w   = (const float*)d_in[1];
  const float* n1b   = (const float*)d_in[2];
  const float* qkvw  = (const float*)d_in[3];
  const float* qkvb  = (const float*)d_in[4];
  const float* projw = (const float*)d_in[5];
  const float* projb = (const float*)d_in[6];
  const float* n2w   = (const float*)d_in[7];
  const float* n2b   = (const float*)d_in[8];
  const float* w1    = (const float*)d_in[9];
  const float* b1    = (const float*)d_in[10];
  const float* w2    = (const float*)d_in[11];
  const float* b2    = (const float*)d_in[12];
  float* out = (float*)d_out;
  char* ws = (char*)d_ws;

  BF16* wt_qkv  = (BF16*)(ws + OFF_WQKV);
  BF16* wt_proj = (BF16*)(ws + OFF_WPROJ);
  BF16* wt_w1   = (BF16*)(ws + OFF_W1);
  BF16* wt_w2   = (BF16*)(ws + OFF_W2);
  BF16* hbuf    = (BF16*)(ws + OFF_H);
  BF16* qkvbuf  = (BF16*)(ws + OFF_QKV);
  BF16* attnbuf = (BF16*)(ws + OFF_ATTN);
  BF16* mbuf    = (BF16*)(ws + OFF_M);

  wprep_kernel<<<dim3(24, 8), 256, 0, stream>>>(qkvw, wt_qkv, 512, 1536);
  wprep_kernel<<<dim3(8, 8), 256, 0, stream>>>(projw, wt_proj, 512, 512);
  wprep_kernel<<<dim3(32, 8), 256, 0, stream>>>(w1, wt_w1, 512, 2048);
  wprep_kernel<<<dim3(8, 32), 256, 0, stream>>>(w2, wt_w2, 2048, 512);

  ln_kernel<<<16384, 256, 0, stream>>>(x, n1w, n1b, hbuf);
  gemm256<1, 0, 512><<<dim3(6, 256), 512, 0, stream>>>(hbuf, wt_qkv, qkvb, nullptr, nullptr, qkvbuf, 1536);
  attn_kernel<<<8192, 64, 0, stream>>>(qkvbuf, attnbuf);
  gemm256<0, 2, 512><<<dim3(2, 256), 512, 0, stream>>>(attnbuf, wt_proj, projb, x, out, nullptr, 512);
  ln_kernel<<<16384, 256, 0, stream>>>(out, n2w, n2b, hbuf);
  gemm256<0, 1, 512><<<dim3(8, 256), 512, 0, stream>>>(hbuf, wt_w1, b1, nullptr, nullptr, mbuf, 2048);
  gemm256<0, 3, 2048><<<dim3(2, 256), 512, 0, stream>>>(mbuf, wt_w2, b2, nullptr, out, nullptr, 512);
}